// Round 8
// baseline (149.975 us; speedup 1.0000x reference)
//
#include <hip/hip_runtime.h>
#include <hip/hip_bf16.h>

typedef __attribute__((ext_vector_type(4))) short bf16x4;   // 4 bf16 = 2 VGPR
typedef __attribute__((ext_vector_type(4))) float f32x4;
typedef __attribute__((ext_vector_type(4))) int i32x4;

#define LOG2E 1.4426950408889634f
#define SMAX 8.0f   // fixed softmax shift (log2 domain); exact after normalization

static __device__ inline f32x4 mfma16(bf16x4 a, bf16x4 b, f32x4 c) {
  return __builtin_amdgcn_mfma_f32_16x16x16bf16_1k(a, b, c, 0, 0, 0);
}
static __device__ inline ushort f2bfu(float f) {
  __hip_bfloat16 h = __float2bfloat16(f);
  return *(ushort*)&h;
}

// ---------------------------------------------------------------------------
// Input projections: C = (x @ W + b) * alpha. x f32 [8192x128], C bf16.
// MODE 0: row-major C[m][col]           (Q)
// MODE 1: per-head K^T16: Kt[((b*8+h)*1024 + n)*16 + k]   (h=nt, k=lm)
// MODE 2: block-transposed V^T: Vt[((b*8+h)*16 + (n>>6))*1024 + d*64 + (n&63)]
// ---------------------------------------------------------------------------
template <int MODE>
__global__ __launch_bounds__(256) void gemm_in(
    const float* __restrict__ A, const float* __restrict__ W,
    const float* __restrict__ bias, ushort* __restrict__ C, float alpha) {
  const int tid = threadIdx.x;
  const int l = tid & 63, w = tid >> 6;
  const int lm = l & 15, g = l >> 4;
  const int tile = blockIdx.x * 4 + w;      // 0..4095
  const int mt = tile >> 3, nt = tile & 7;  // 512 x 8 tiles
  const int row = mt * 16 + lm;
  const int col = nt * 16 + lm;

  f32x4 acc = {0.f, 0.f, 0.f, 0.f};
#pragma unroll
  for (int ks = 0; ks < 8; ++ks) {
    f32x4 av = *(const f32x4*)(A + (size_t)row * 128 + ks * 16 + g * 4);
    bf16x4 a;
    a[0] = (short)f2bfu(av[0]); a[1] = (short)f2bfu(av[1]);
    a[2] = (short)f2bfu(av[2]); a[3] = (short)f2bfu(av[3]);
    const float* wp = W + (size_t)(ks * 16 + g * 4) * 128 + col;
    bf16x4 b;
    b[0] = (short)f2bfu(wp[0]);   b[1] = (short)f2bfu(wp[128]);
    b[2] = (short)f2bfu(wp[256]); b[3] = (short)f2bfu(wp[384]);
    acc = mfma16(a, b, acc);
  }
  const float bv = bias[col];
  float v0 = (acc[0] + bv) * alpha, v1 = (acc[1] + bv) * alpha;
  float v2 = (acc[2] + bv) * alpha, v3 = (acc[3] + bv) * alpha;
  const int mb = mt * 16;

  if constexpr (MODE == 0) {
    C[(size_t)(mb + g * 4 + 0) * 128 + col] = f2bfu(v0);
    C[(size_t)(mb + g * 4 + 1) * 128 + col] = f2bfu(v1);
    C[(size_t)(mb + g * 4 + 2) * 128 + col] = f2bfu(v2);
    C[(size_t)(mb + g * 4 + 3) * 128 + col] = f2bfu(v3);
  } else if constexpr (MODE == 1) {
    const size_t kb = ((size_t)((mb >> 10) * 8 + nt) * 1024 + ((mb & 1023) + g * 4));
    C[(kb + 0) * 16 + lm] = f2bfu(v0);
    C[(kb + 1) * 16 + lm] = f2bfu(v1);
    C[(kb + 2) * 16 + lm] = f2bfu(v2);
    C[(kb + 3) * 16 + lm] = f2bfu(v3);
  } else {
    const size_t addr = ((size_t)((mb >> 10) * 8 + nt) * 16 + ((mb & 1023) >> 6)) * 1024
                        + (size_t)lm * 64 + (mb & 63) + g * 4;
    bf16x4 vv;
    vv[0] = (short)f2bfu(v0); vv[1] = (short)f2bfu(v1);
    vv[2] = (short)f2bfu(v2); vv[3] = (short)f2bfu(v3);
    *(bf16x4*)(C + addr) = vv;
  }
}

// ---------------------------------------------------------------------------
// Fused graph attention. One WG = (b, 16-row m-tile); 8 waves = 8 heads.
// 16 iterations x 64 columns. adj/edge: QUAD-buffered LDS, staging prefetch
// depth 4, sreg[4] statically indexed (full unroll, buf = ct&3 constant).
// K/V direct loads (L2-resident). Fixed-shift log2-domain softmax.
// Register-lean: no K/V reg double-buffer, no stagger, pointer-bump addrs.
// ---------------------------------------------------------------------------
#define STI 68  // LDS row stride (ints)

__global__ __launch_bounds__(512, 4) void attn_kernel(
    const ushort* __restrict__ Qs, const ushort* __restrict__ Kt,
    const ushort* __restrict__ Vt, const int* __restrict__ adj,
    const float* __restrict__ edge, const float* __restrict__ We,
    ushort* __restrict__ AO) {
  __shared__ int adj_lds[4][16 * STI];
  __shared__ int edge_lds[4][16 * STI];   // float bits as int

  const int tid = threadIdx.x;
  const int l = tid & 63, h = tid >> 6;
  const int lm = l & 15, g = l >> 4;
  const int b = blockIdx.x >> 6;
  const int m0 = (blockIdx.x & 63) * 16;

  const float Weh = We[h] * LOG2E;
  // B-frag of S^T = K.Q^T : lane holds Q[m0+lm][k=4g+j] (0.25*log2e folded)
  const bf16x4 qf = *(const bf16x4*)(Qs + ((size_t)b * 1024 + m0 + lm) * 128 + h * 16 + g * 4);

  const ushort* kp = Kt + ((size_t)b * 8 + h) * 16384 + (size_t)lm * 16 + g * 4;  // += 1024/iter
  const ushort* vp = Vt + ((size_t)b * 8 + h) * 16384 + (size_t)lm * 64 + g * 4;  // += 1024/iter

  // staging roles: tid<256 -> adj, else edge; one b128 per tile each
  const int sr = (tid & 255) >> 4, sc = (tid & 15) * 4;
  const bool s_adj = (tid < 256);
  const int* sgp = (s_adj ? adj : (const int*)edge)
                   + (size_t)b * 1048576 + (size_t)(m0 + sr) * 1024 + sc;  // += 64/iter
  const int lofs = sr * STI + sc;

  // prologue: tile0 -> LDS buf0; tiles 1..4 -> sreg slots (tile & 3)
  {
    i32x4 v = *(const i32x4*)sgp;
    if (s_adj) *(i32x4*)&adj_lds[0][lofs] = v;
    else       *(i32x4*)&edge_lds[0][lofs] = v;
  }
  i32x4 sreg[4];
  sreg[1] = *(const i32x4*)(sgp + 1 * 64);
  sreg[2] = *(const i32x4*)(sgp + 2 * 64);
  sreg[3] = *(const i32x4*)(sgp + 3 * 64);
  sreg[0] = *(const i32x4*)(sgp + 4 * 64);

  float lsum = 0.f;
  f32x4 oacc = {0.f, 0.f, 0.f, 0.f};
  const f32x4 cinit = {-SMAX, -SMAX, -SMAX, -SMAX};

#pragma unroll
  for (int ct = 0; ct < 16; ++ct) {
    const int buf = ct & 3;          // compile-time under full unroll
    const int nbuf = (ct + 1) & 3;
    __syncthreads();                 // buf staged & visible; nbuf free to write

    // (a) LDS-write tile ct+1 (its load was issued 4 iterations ago)
    if (ct < 15) {
      if (s_adj) *(i32x4*)&adj_lds[nbuf][lofs] = sreg[nbuf];
      else       *(i32x4*)&edge_lds[nbuf][lofs] = sreg[nbuf];
    }
    // (b) reuse freed slot: issue staging load for tile ct+5
    if (ct + 5 < 16) sreg[nbuf] = *(const i32x4*)(sgp + (ct + 5) * 64);

    // (c) K/V loads for this tile (L2-hot; issued before use, covered by TLP)
    bf16x4 kfr[4], vfr[4];
#pragma unroll
    for (int t = 0; t < 4; ++t) {
      kfr[t] = *(const bf16x4*)(kp + (size_t)ct * 1024 + t * 256); // K[n0+16t+lm][4g+j]
      vfr[t] = *(const bf16x4*)(vp + (size_t)ct * 1024 + t * 16);  // V^T[lm][n0+16t+4g+j]
    }
    // (d) S^T = K.Q^T (pre-shifted by -SMAX): lane l, reg j -> (n, m=m0+lm)
    f32x4 st[4];
#pragma unroll
    for (int t = 0; t < 4; ++t) st[t] = mfma16(kfr[t], qf, cinit);

#pragma unroll
    for (int t = 0; t < 4; ++t) {
      const i32x4 a4 = *(const i32x4*)&adj_lds[buf][lm * STI + t * 16 + g * 4];
      const i32x4 e4i = *(const i32x4*)&edge_lds[buf][lm * STI + t * 16 + g * 4];
      const f32x4 e4 = *(const f32x4*)&e4i;
      bf16x4 pf4;
#pragma unroll
      for (int j = 0; j < 4; ++j) {
        float p = __builtin_amdgcn_exp2f(fmaf(e4[j], Weh, st[t][j]));
        p = (a4[j] == 0) ? 0.f : p;
        lsum += p;
        pf4[j] = (short)f2bfu(p);
      }
      // P^T (S^T C/D layout) == B-frag of PV; O^T[d=4g+r][m=lm]
      oacc = mfma16(vfr[t], pf4, oacc);
    }
  }

  // row-sum across lane groups {lm, lm+16, lm+32, lm+48}
  lsum += __shfl_xor(lsum, 16, 64);
  lsum += __shfl_xor(lsum, 32, 64);
  const float inv = 1.0f / lsum;
  bf16x4 ov;
  ov[0] = (short)f2bfu(oacc[0] * inv);
  ov[1] = (short)f2bfu(oacc[1] * inv);
  ov[2] = (short)f2bfu(oacc[2] * inv);
  ov[3] = (short)f2bfu(oacc[3] * inv);
  *(bf16x4*)(AO + ((size_t)b * 1024 + m0 + lm) * 128 + h * 16 + g * 4) = ov;
}

// ---------------------------------------------------------------------------
// Output projection: AO (bf16) @ Wo + bo -> f32 out.
// ---------------------------------------------------------------------------
__global__ __launch_bounds__(256) void gemm_out(
    const ushort* __restrict__ A, const float* __restrict__ W,
    const float* __restrict__ bias, float* __restrict__ C) {
  const int tid = threadIdx.x;
  const int l = tid & 63, w = tid >> 6;
  const int lm = l & 15, g = l >> 4;
  const int tile = blockIdx.x * 4 + w;
  const int mt = tile >> 3, nt = tile & 7;
  const int row = mt * 16 + lm;
  const int col = nt * 16 + lm;

  f32x4 acc = {0.f, 0.f, 0.f, 0.f};
#pragma unroll
  for (int ks = 0; ks < 8; ++ks) {
    bf16x4 a = *(const bf16x4*)(A + (size_t)row * 128 + ks * 16 + g * 4);
    const float* wp = W + (size_t)(ks * 16 + g * 4) * 128 + col;
    bf16x4 bf;
    bf[0] = (short)f2bfu(wp[0]);   bf[1] = (short)f2bfu(wp[128]);
    bf[2] = (short)f2bfu(wp[256]); bf[3] = (short)f2bfu(wp[384]);
    acc = mfma16(a, bf, acc);
  }
  const float bv = bias[col];
#pragma unroll
  for (int r = 0; r < 4; ++r)
    C[(size_t)(mt * 16 + g * 4 + r) * 128 + col] = acc[r] + bv;
}

extern "C" void kernel_launch(void* const* d_in, const int* in_sizes, int n_in,
                              void* d_out, int out_size, void* d_ws, size_t ws_size,
                              hipStream_t stream) {
  const float* x   = (const float*)d_in[0];
  const int*   adj = (const int*)d_in[1];
  const float* ew  = (const float*)d_in[2];
  const float* Wq  = (const float*)d_in[3];
  const float* bq  = (const float*)d_in[4];
  const float* Wk  = (const float*)d_in[5];
  const float* bk  = (const float*)d_in[6];
  const float* Wv  = (const float*)d_in[7];
  const float* bv  = (const float*)d_in[8];
  const float* Wo  = (const float*)d_in[9];
  const float* bo  = (const float*)d_in[10];
  const float* We  = (const float*)d_in[11];
  // be (d_in[12]) dropped: softmax(x + c) == softmax(x)

  const size_t MN = (size_t)8 * 1024 * 128;  // 1M elements
  ushort* Qs = (ushort*)d_ws;
  ushort* Kt = Qs + MN;
  ushort* Vt = Kt + MN;
  ushort* AO = Vt + MN;

  gemm_in<0><<<1024, 256, 0, stream>>>(x, Wq, bq, Qs, 0.25f * LOG2E);
  gemm_in<1><<<1024, 256, 0, stream>>>(x, Wk, bk, Kt, 1.0f);
  gemm_in<2><<<1024, 256, 0, stream>>>(x, Wv, bv, Vt, 1.0f);
  attn_kernel<<<512, 512, 0, stream>>>(Qs, Kt, Vt, adj, ew, We, AO);
  gemm_out<<<1024, 256, 0, stream>>>(AO, Wo, bo, (float*)d_out);
}

// Round 9
// 67.313 us; speedup vs baseline: 2.2280x; 2.2280x over previous
//
#include <hip/hip_runtime.h>
#include <hip/hip_bf16.h>

typedef __attribute__((ext_vector_type(4))) short bf16x4;   // 4 bf16 = 2 VGPR
typedef __attribute__((ext_vector_type(4))) float f32x4;
typedef __attribute__((ext_vector_type(4))) int i32x4;

#define LOG2E 1.4426950408889634f
#define SMAX 8.0f   // fixed softmax shift (log2 domain); exact after normalization

static __device__ inline f32x4 mfma16(bf16x4 a, bf16x4 b, f32x4 c) {
  return __builtin_amdgcn_mfma_f32_16x16x16bf16_1k(a, b, c, 0, 0, 0);
}
static __device__ inline ushort f2bfu(float f) {
  __hip_bfloat16 h = __float2bfloat16(f);
  return *(ushort*)&h;
}
// async global->LDS DMA, 16 B per lane; dst = wave-uniform base + lane*16
static __device__ __forceinline__ void dma16(const void* g, void* l) {
  __builtin_amdgcn_global_load_lds(
      (const __attribute__((address_space(1))) void*)g,
      (__attribute__((address_space(3))) void*)l, 16, 0, 0);
}

// ---------------------------------------------------------------------------
// Input projections: C = (x @ W + b) * alpha. x f32 [8192x128], C bf16.
// MODE 0: row-major C[m][col]           (Q)
// MODE 1: per-head K^T16: Kt[((b*8+h)*1024 + n)*16 + k]   (h=nt, k=lm)
// MODE 2: block-transposed V^T: Vt[((b*8+h)*16 + (n>>6))*1024 + d*64 + (n&63)]
// ---------------------------------------------------------------------------
template <int MODE>
__global__ __launch_bounds__(256) void gemm_in(
    const float* __restrict__ A, const float* __restrict__ W,
    const float* __restrict__ bias, ushort* __restrict__ C, float alpha) {
  const int tid = threadIdx.x;
  const int l = tid & 63, w = tid >> 6;
  const int lm = l & 15, g = l >> 4;
  const int tile = blockIdx.x * 4 + w;      // 0..4095
  const int mt = tile >> 3, nt = tile & 7;  // 512 x 8 tiles
  const int row = mt * 16 + lm;
  const int col = nt * 16 + lm;

  f32x4 acc = {0.f, 0.f, 0.f, 0.f};
#pragma unroll
  for (int ks = 0; ks < 8; ++ks) {
    f32x4 av = *(const f32x4*)(A + (size_t)row * 128 + ks * 16 + g * 4);
    bf16x4 a;
    a[0] = (short)f2bfu(av[0]); a[1] = (short)f2bfu(av[1]);
    a[2] = (short)f2bfu(av[2]); a[3] = (short)f2bfu(av[3]);
    const float* wp = W + (size_t)(ks * 16 + g * 4) * 128 + col;
    bf16x4 b;
    b[0] = (short)f2bfu(wp[0]);   b[1] = (short)f2bfu(wp[128]);
    b[2] = (short)f2bfu(wp[256]); b[3] = (short)f2bfu(wp[384]);
    acc = mfma16(a, b, acc);
  }
  const float bv = bias[col];
  float v0 = (acc[0] + bv) * alpha, v1 = (acc[1] + bv) * alpha;
  float v2 = (acc[2] + bv) * alpha, v3 = (acc[3] + bv) * alpha;
  const int mb = mt * 16;

  if constexpr (MODE == 0) {
    C[(size_t)(mb + g * 4 + 0) * 128 + col] = f2bfu(v0);
    C[(size_t)(mb + g * 4 + 1) * 128 + col] = f2bfu(v1);
    C[(size_t)(mb + g * 4 + 2) * 128 + col] = f2bfu(v2);
    C[(size_t)(mb + g * 4 + 3) * 128 + col] = f2bfu(v3);
  } else if constexpr (MODE == 1) {
    const size_t kb = ((size_t)((mb >> 10) * 8 + nt) * 1024 + ((mb & 1023) + g * 4));
    C[(kb + 0) * 16 + lm] = f2bfu(v0);
    C[(kb + 1) * 16 + lm] = f2bfu(v1);
    C[(kb + 2) * 16 + lm] = f2bfu(v2);
    C[(kb + 3) * 16 + lm] = f2bfu(v3);
  } else {
    const size_t addr = ((size_t)((mb >> 10) * 8 + nt) * 16 + ((mb & 1023) >> 6)) * 1024
                        + (size_t)lm * 64 + (mb & 63) + g * 4;
    bf16x4 vv;
    vv[0] = (short)f2bfu(v0); vv[1] = (short)f2bfu(v1);
    vv[2] = (short)f2bfu(v2); vv[3] = (short)f2bfu(v3);
    *(bf16x4*)(C + addr) = vv;
  }
}

// ---------------------------------------------------------------------------
// Fused graph attention, all-DMA pipeline. One WG = (b, 16-row m-tile);
// 8 waves = 8 heads. 16 tiles x 64 columns. EVERY in-loop global load is a
// global_load_lds DMA (5 per wave per tile: K x2, V x2, adj-or-edge x1), so
// vmcnt counts only DMAs -> counted s_waitcnt vmcnt(5) keeps the next tile
// in flight across the barrier (never drains). 3 LDS buffers x 40 KB.
// V and adj/edge global sources pre-swizzled (even XOR) for LDS bank spread.
// ---------------------------------------------------------------------------
#define BUFB 40960  // bytes per LDS buffer: K 16K | V 16K | adj 4K | edge 4K

__global__ __launch_bounds__(512) void attn_kernel(
    const ushort* __restrict__ Qs, const ushort* __restrict__ Kt,
    const ushort* __restrict__ Vt, const int* __restrict__ adj,
    const float* __restrict__ edge, const float* __restrict__ We,
    ushort* __restrict__ AO) {
  __shared__ __align__(16) char smem[3 * BUFB];

  const int tid = threadIdx.x;
  const int l = tid & 63, h = tid >> 6;
  const int lm = l & 15, g = l >> 4;
  const int b = blockIdx.x >> 6;
  const int m0 = (blockIdx.x & 63) * 16;

  const float Weh = We[h] * LOG2E;
  // B-frag of S^T = K.Q^T : lane holds Q[m0+lm][k=4g+j] (0.25*log2e folded)
  const bf16x4 qf = *(const bf16x4*)(Qs + ((size_t)b * 1024 + m0 + lm) * 128 + h * 16 + g * 4);

  // DMA sources
  const ushort* kt0 = Kt + ((size_t)b * 8 + h) * 16384 + l * 8;      // + T*1024
  const int dv = l >> 3, mv = l & 7;                                  // V swizzle
  const int voff = dv * 64 + (((mv * 2) ^ (dv & 6)) * 4);             // elements
  const ushort* vt0 = Vt + ((size_t)b * 8 + h) * 16384 + voff;       // + T*1024
  const int hh = h & 3;
  const int sr = hh * 4 + (l >> 4);                                   // tile row
  const int sci = ((l & 15) * 4) ^ ((sr & 7) << 3);                   // swz col (ints)
  const int* ssrc = ((h < 4) ? adj : (const int*)edge)
                    + (size_t)b * 1048576 + (size_t)(m0 + sr) * 1024 + sci;  // + T*64

  // DMA dests (wave-uniform)
  char* kdst = smem + h * 2048;
  char* vdst = smem + 16384 + h * 2048;
  char* sdst = smem + ((h < 4) ? 32768 : 36864) + hh * 1024;

  float lsum = 0.f;
  f32x4 oacc = {0.f, 0.f, 0.f, 0.f};
  const f32x4 cinit = {-SMAX, -SMAX, -SMAX, -SMAX};

  auto stage = [&](int T, int bi) {
    const int bo = bi * BUFB;
    const ushort* ks = kt0 + (size_t)T * 1024;
    const ushort* vs = vt0 + (size_t)T * 1024;
    dma16(ks,        kdst + bo);
    dma16(ks + 512,  kdst + bo + 1024);
    dma16(vs,        vdst + bo);
    dma16(vs + 512,  vdst + bo + 1024);
    dma16(ssrc + T * 64, sdst + bo);
  };

  auto compute = [&](int bi) {
    const char* base = smem + bi * BUFB;
    const char* kls = base + h * 2048;
    const char* vls = base + 16384 + h * 2048;
    const int* als = (const int*)(base + 32768);
    const int* els = (const int*)(base + 36864);
    const int xorv = (lm & 7) << 3;

    f32x4 st[4];
    bf16x4 vfr[4];
#pragma unroll
    for (int t = 0; t < 4; ++t) {
      // K[n0+16t+lm][4g+j] : element (16t+lm)*16 + 4g
      bf16x4 kf = *(const bf16x4*)(kls + (t * 16 + lm) * 32 + g * 8);
      st[t] = mfma16(kf, qf, cinit);
      // V^T[d=lm][n=16t+4g+j] : granule q=4t+g stored at q^(lm&6)
      vfr[t] = *(const bf16x4*)(vls + lm * 128 + (((t * 4 + g) ^ (lm & 6)) * 8));
    }
#pragma unroll
    for (int t = 0; t < 4; ++t) {
      const int ci = (t * 16 + g * 4) ^ xorv;
      const i32x4 a4 = *(const i32x4*)(als + lm * 64 + ci);
      const i32x4 e4i = *(const i32x4*)(els + lm * 64 + ci);
      const f32x4 e4 = *(const f32x4*)&e4i;
      bf16x4 pf4;
#pragma unroll
      for (int j = 0; j < 4; ++j) {
        float p = __builtin_amdgcn_exp2f(fmaf(e4[j], Weh, st[t][j]));
        p = (a4[j] == 0) ? 0.f : p;
        lsum += p;
        pf4[j] = (short)f2bfu(p);
      }
      // P^T (S^T C/D layout) == B-frag of PV; O^T[d=4g+r][m=lm]
      oacc = mfma16(vfr[t], pf4, oacc);
    }
  };

  // prologue: tiles 0,1 in flight
  stage(0, 0);
  stage(1, 1);

  int cur = 0;
  for (int ct = 0; ct < 15; ++ct) {
    // wait own tile-ct DMAs (5 stay in flight for tile ct+1) then sync waves
    asm volatile("s_waitcnt vmcnt(5)" ::: "memory");
    __builtin_amdgcn_s_barrier();
    __builtin_amdgcn_sched_barrier(0);
    // all waves vacated buffer (cur+2)%3 -> refill it with tile ct+2
    if (ct < 14) stage(ct + 2, cur >= 1 ? cur - 1 : 2);
    compute(cur);
    cur = (cur == 2) ? 0 : cur + 1;
  }
  asm volatile("s_waitcnt vmcnt(0)" ::: "memory");
  __builtin_amdgcn_s_barrier();
  __builtin_amdgcn_sched_barrier(0);
  compute(cur);

  // row-sum across lane groups {lm, lm+16, lm+32, lm+48}
  lsum += __shfl_xor(lsum, 16, 64);
  lsum += __shfl_xor(lsum, 32, 64);
  const float inv = 1.0f / lsum;
  bf16x4 ov;
  ov[0] = (short)f2bfu(oacc[0] * inv);
  ov[1] = (short)f2bfu(oacc[1] * inv);
  ov[2] = (short)f2bfu(oacc[2] * inv);
  ov[3] = (short)f2bfu(oacc[3] * inv);
  *(bf16x4*)(AO + ((size_t)b * 1024 + m0 + lm) * 128 + h * 16 + g * 4) = ov;
}

// ---------------------------------------------------------------------------
// Output projection: AO (bf16) @ Wo + bo -> f32 out.
// ---------------------------------------------------------------------------
__global__ __launch_bounds__(256) void gemm_out(
    const ushort* __restrict__ A, const float* __restrict__ W,
    const float* __restrict__ bias, float* __restrict__ C) {
  const int tid = threadIdx.x;
  const int l = tid & 63, w = tid >> 6;
  const int lm = l & 15, g = l >> 4;
  const int tile = blockIdx.x * 4 + w;
  const int mt = tile >> 3, nt = tile & 7;
  const int row = mt * 16 + lm;
  const int col = nt * 16 + lm;

  f32x4 acc = {0.f, 0.f, 0.f, 0.f};
#pragma unroll
  for (int ks = 0; ks < 8; ++ks) {
    bf16x4 a = *(const bf16x4*)(A + (size_t)row * 128 + ks * 16 + g * 4);
    const float* wp = W + (size_t)(ks * 16 + g * 4) * 128 + col;
    bf16x4 bf;
    bf[0] = (short)f2bfu(wp[0]);   bf[1] = (short)f2bfu(wp[128]);
    bf[2] = (short)f2bfu(wp[256]); bf[3] = (short)f2bfu(wp[384]);
    acc = mfma16(a, bf, acc);
  }
  const float bv = bias[col];
#pragma unroll
  for (int r = 0; r < 4; ++r)
    C[(size_t)(mt * 16 + g * 4 + r) * 128 + col] = acc[r] + bv;
}

extern "C" void kernel_launch(void* const* d_in, const int* in_sizes, int n_in,
                              void* d_out, int out_size, void* d_ws, size_t ws_size,
                              hipStream_t stream) {
  const float* x   = (const float*)d_in[0];
  const int*   adj = (const int*)d_in[1];
  const float* ew  = (const float*)d_in[2];
  const float* Wq  = (const float*)d_in[3];
  const float* bq  = (const float*)d_in[4];
  const float* Wk  = (const float*)d_in[5];
  const float* bk  = (const float*)d_in[6];
  const float* Wv  = (const float*)d_in[7];
  const float* bv  = (const float*)d_in[8];
  const float* Wo  = (const float*)d_in[9];
  const float* bo  = (const float*)d_in[10];
  const float* We  = (const float*)d_in[11];
  // be (d_in[12]) dropped: softmax(x + c) == softmax(x)

  const size_t MN = (size_t)8 * 1024 * 128;  // 1M elements
  ushort* Qs = (ushort*)d_ws;
  ushort* Kt = Qs + MN;
  ushort* Vt = Kt + MN;
  ushort* AO = Vt + MN;

  gemm_in<0><<<1024, 256, 0, stream>>>(x, Wq, bq, Qs, 0.25f * LOG2E);
  gemm_in<1><<<1024, 256, 0, stream>>>(x, Wk, bk, Kt, 1.0f);
  gemm_in<2><<<1024, 256, 0, stream>>>(x, Wv, bv, Vt, 1.0f);
  attn_kernel<<<512, 512, 0, stream>>>(Qs, Kt, Vt, adj, ew, We, AO);
  gemm_out<<<1024, 256, 0, stream>>>(AO, Wo, bo, (float*)d_out);
}